// Round 1
// baseline (292.154 us; speedup 1.0000x reference)
//
#include <hip/hip_runtime.h>
#include <math.h>

#define NCLS  1000
#define NROWS 16384
#define INV_TEMP 0.5f
#define NEG_INF (-INFINITY)

// merge two ordered top-2 pairs: (a1>=a2) U (b1>=b2) -> (a1,a2)
__device__ __forceinline__ void merge2(float& a1, float& a2, float b1, float b2) {
    const float mn = fminf(a1, b1);
    a1 = fmaxf(a1, b1);
    a2 = fmaxf(mn, fmaxf(a2, b2));
}

// top-2 over one row held in 4 float4 regs (v3 tail pre-masked), then
// 6-step wave butterfly -> wave-uniform (m1,m2)
__device__ __forceinline__ void top2_wave(const float4& v0, const float4& v1,
                                          const float4& v2, const float4& v3,
                                          float& m1, float& m2)
{
    float t1[4], t2[4];
    const float4 vv[4] = {v0, v1, v2, v3};
    #pragma unroll
    for (int i = 0; i < 4; ++i) {
        const float hi1 = fmaxf(vv[i].x, vv[i].y), lo1 = fminf(vv[i].x, vv[i].y);
        const float hi2 = fmaxf(vv[i].z, vv[i].w), lo2 = fminf(vv[i].z, vv[i].w);
        t1[i] = fmaxf(hi1, hi2);
        t2[i] = fmaxf(fminf(hi1, hi2), fmaxf(lo1, lo2));
    }
    merge2(t1[0], t2[0], t1[1], t2[1]);
    merge2(t1[2], t2[2], t1[3], t2[3]);
    merge2(t1[0], t2[0], t1[2], t2[2]);
    m1 = t1[0]; m2 = t2[0];
    #pragma unroll
    for (int off = 32; off >= 1; off >>= 1) {
        const float q1 = __shfl_xor(m1, off, 64);
        const float q2 = __shfl_xor(m2, off, 64);
        merge2(m1, m2, q1, q2);
    }
}

// target value is already resident in the wave's registers: select the
// component (tgt is wave-uniform -> cndmask chain) and broadcast from the
// owning lane. chunk 3 source lanes are always < 58, so tail-masking is safe.
__device__ __forceinline__ float extract_tv(const float4& v0, const float4& v1,
                                            const float4& v2, const float4& v3,
                                            int tgt)
{
    const int q = tgt >> 2, comp = tgt & 3, chunk = q >> 6, src = q & 63;
    const float4 sel = (chunk == 0) ? v0 : (chunk == 1) ? v1
                     : (chunk == 2) ? v2 : v3;
    const float c = (comp == 0) ? sel.x : (comp == 1) ? sel.y
                  : (comp == 2) ? sel.z : sel.w;
    return __shfl(c, src, 64);
}

// One wave per ROW, all 5 matrices. 20 dwordx4 loads issued up front (5x the
// MLP of the previous one-wave-per-(row,mat) version), no dependent target
// gather, no __syncthreads, softmax fused in (margins are wave-uniform after
// the butterfly). Writes 5 softmax outputs + 1 wavemax entry per row.
__global__ __launch_bounds__(256) void fused_margin_softmax(
    const float* __restrict__ o1, const float* __restrict__ o2,
    const float* __restrict__ o3, const float* __restrict__ o4,
    const float* __restrict__ mim, const int* __restrict__ targets,
    float* __restrict__ out, float* __restrict__ wavemax)
{
    const int lane = threadIdx.x & 63;
    const int row  = blockIdx.x * 4 + (threadIdx.x >> 6);   // wave-uniform
    const int i3   = (lane < 58) ? (192 + lane) : 249;

    const float4* pa = (const float4*)(o1  + (size_t)row * NCLS);
    const float4* pb = (const float4*)(o2  + (size_t)row * NCLS);
    const float4* pc = (const float4*)(o3  + (size_t)row * NCLS);
    const float4* pd = (const float4*)(o4  + (size_t)row * NCLS);
    const float4* pe = (const float4*)(mim + (size_t)row * NCLS);

    // issue all 20 row loads + the tiny (L2-hot) target-index load up front
    float4 a0 = pa[lane], a1 = pa[64 + lane], a2 = pa[128 + lane], a3 = pa[i3];
    float4 b0 = pb[lane], b1 = pb[64 + lane], b2 = pb[128 + lane], b3 = pb[i3];
    float4 c0 = pc[lane], c1 = pc[64 + lane], c2 = pc[128 + lane], c3 = pc[i3];
    float4 d0 = pd[lane], d1 = pd[64 + lane], d2 = pd[128 + lane], d3 = pd[i3];
    float4 e0 = pe[lane], e1 = pe[64 + lane], e2 = pe[128 + lane], e3 = pe[i3];
    const int tgt = targets[row];

    if (lane >= 58) {
        const float4 n4 = make_float4(NEG_INF, NEG_INF, NEG_INF, NEG_INF);
        a3 = n4; b3 = n4; c3 = n4; d3 = n4; e3 = n4;
    }

    float m1, m2, tv, rowmax;
    float g0, g1, g2, g3, g4;

    tv = extract_tv(a0, a1, a2, a3, tgt);
    top2_wave(a0, a1, a2, a3, m1, m2);
    g0 = (m1 == tv) ? (m1 - m2) : 0.0f;
    rowmax = m1;

    tv = extract_tv(b0, b1, b2, b3, tgt);
    top2_wave(b0, b1, b2, b3, m1, m2);
    g1 = (m1 == tv) ? (m1 - m2) : 0.0f;
    rowmax = fmaxf(rowmax, m1);

    tv = extract_tv(c0, c1, c2, c3, tgt);
    top2_wave(c0, c1, c2, c3, m1, m2);
    g2 = (m1 == tv) ? (m1 - m2) : 0.0f;
    rowmax = fmaxf(rowmax, m1);

    tv = extract_tv(d0, d1, d2, d3, tgt);
    top2_wave(d0, d1, d2, d3, m1, m2);
    g3 = (m1 == tv) ? (m1 - m2) : 0.0f;
    rowmax = fmaxf(rowmax, m1);

    tv = extract_tv(e0, e1, e2, e3, tgt);
    top2_wave(e0, e1, e2, e3, m1, m2);
    g4 = (m1 == tv) ? (m1 - m2) : 0.0f;     // mimic: excluded from rowmax

    // fused softmax over the 5 wave-uniform margins (same arithmetic as ref)
    const float q0 = g0 * INV_TEMP, q1 = g1 * INV_TEMP, q2 = g2 * INV_TEMP,
                q3 = g3 * INV_TEMP, q4 = g4 * INV_TEMP;
    const float pm = fmaxf(fmaxf(fmaxf(q0, q1), fmaxf(q2, q3)), q4);
    const float x0 = expf(q0 - pm), x1 = expf(q1 - pm), x2 = expf(q2 - pm),
                x3 = expf(q3 - pm), x4 = expf(q4 - pm);
    const float inv = 1.0f / (x0 + x1 + x2 + x3 + x4);

    if (lane < 5) {
        const float r = (lane == 0) ? x0 : (lane == 1) ? x1 : (lane == 2) ? x2
                      : (lane == 3) ? x3 : x4;
        out[1 + (size_t)row * 5 + lane] = r * inv;
    }
    if (lane == 5) wavemax[row] = rowmax;
}

// Single block of 1024 threads reduces wavemax[16384] -> out[0]. Tiny.
__global__ __launch_bounds__(1024) void final_max_kernel(
    const float* __restrict__ wavemax, float* __restrict__ out)
{
    const float4* w4 = (const float4*)wavemax;
    float m = NEG_INF;
    #pragma unroll
    for (int i = 0; i < (NROWS / 4) / 1024; ++i) {   // 4 iterations, coalesced
        const float4 v = w4[threadIdx.x + i * 1024];
        m = fmaxf(fmaxf(fmaxf(m, v.x), v.y), fmaxf(v.z, v.w));
    }
    #pragma unroll
    for (int off = 32; off >= 1; off >>= 1)
        m = fmaxf(m, __shfl_xor(m, off, 64));
    __shared__ float s[16];
    const int lane = threadIdx.x & 63, wid = threadIdx.x >> 6;
    if (lane == 0) s[wid] = m;
    __syncthreads();
    if (threadIdx.x == 0) {
        float mm = s[0];
        #pragma unroll
        for (int i = 1; i < 16; ++i) mm = fmaxf(mm, s[i]);
        out[0] = mm;
    }
}

extern "C" void kernel_launch(void* const* d_in, const int* in_sizes, int n_in,
                              void* d_out, int out_size, void* d_ws, size_t ws_size,
                              hipStream_t stream) {
    const float* o1  = (const float*)d_in[0];
    const float* o2  = (const float*)d_in[1];
    const float* o3  = (const float*)d_in[2];
    const float* o4  = (const float*)d_in[3];
    const float* mim = (const float*)d_in[4];
    const int*   tgt = (const int*)d_in[5];

    float* out = (float*)d_out;
    float* wavemax = (float*)d_ws;                   // NROWS floats (64 KB)

    fused_margin_softmax<<<NROWS / 4, 256, 0, stream>>>(o1, o2, o3, o4, mim, tgt,
                                                        out, wavemax);
    final_max_kernel<<<1, 1024, 0, stream>>>(wavemax, out);
}